// Round 7
// baseline (591.310 us; speedup 1.0000x reference)
//
#include <hip/hip_runtime.h>
#include <hip/hip_bf16.h>

typedef __attribute__((ext_vector_type(8))) short bf16x8;   // 8 bf16 in 4 VGPRs
typedef __attribute__((ext_vector_type(4))) float f32x4;    // MFMA accumulator
typedef __attribute__((ext_vector_type(4))) int   i32x4;

#define NB 256
#define NT 200
#define NW 200
#define NE 768
#define NH 256
#define NEMB 32
#define KIN 800           // E + EMB
#define G3H 768           // 3*H
#define MROWS 51200       // B*T

__device__ __forceinline__ float bf2f(unsigned short h) {
    return __uint_as_float(((unsigned)h) << 16);
}
__device__ __forceinline__ unsigned short f2bf(float f) {
    unsigned u = __float_as_uint(f);
    u += 0x7fff + ((u >> 16) & 1);   // RNE
    return (unsigned short)(u >> 16);
}
__device__ __forceinline__ float sigm(float x) { return 1.0f / (1.0f + __expf(-x)); }
__device__ __forceinline__ float tanh_fast(float x) {
    float e = __expf(2.0f * x);
    return 1.0f - 2.0f / (e + 1.0f);
}

#if __has_builtin(__builtin_amdgcn_sdot4)
__device__ __forceinline__ int SDOT4(int a, int b, int c) {
    return __builtin_amdgcn_sdot4(a, b, c, false);
}
#else
__device__ __forceinline__ int SDOT4(int a, int b, int c) {   // exact fallback
    #pragma unroll
    for (int j = 0; j < 4; j++)
        c += (int)(signed char)(a >> (8 * j)) * (int)(signed char)(b >> (8 * j));
    return c;
}
#endif

// ---------------------------------------------------------------------------
// prep1: A_bf16[51200][800] = [bf16(inputs) | bf16(emb_table[fix])],
//        W_ih -> bf16 [768][800], W_out -> bf16 [768][256],
//        biasC[768] = b_ih + (row<512 ? b_hh : 0)   (b_hh r,z folded into xg)
// ---------------------------------------------------------------------------
__global__ void prep1(const float* __restrict__ inputs, const int* __restrict__ fix_seq,
                      const float* __restrict__ emb, const float* __restrict__ Wih,
                      const float* __restrict__ Wout, const float* __restrict__ bih,
                      const float* __restrict__ bhh,
                      unsigned short* __restrict__ Abf, unsigned short* __restrict__ Wihbf,
                      unsigned short* __restrict__ Woutbf, float* __restrict__ biasC) {
    const long gid0 = (long)blockIdx.x * blockDim.x + threadIdx.x;
    if (gid0 < G3H) biasC[gid0] = bih[gid0] + (gid0 < 512 ? bhh[gid0] : 0.0f);
    const long NA = (long)MROWS * 100;   // 8 cols per unit
    const long NWU = 768L * 100;
    const long NOU = 768L * 32;
    const long total = NA + NWU + NOU;
    for (long u = gid0; u < total; u += (long)gridDim.x * blockDim.x) {
        bf16x8 v;
        unsigned short* dst;
        if (u < NA) {
            long row = u / 100;
            int c8 = (int)(u % 100) * 8;
            const float* s;
            if (c8 < NE) {
                s = inputs + row * NE + c8;
            } else {
                int fx = fix_seq[row];
                s = emb + (long)fx * NEMB + (c8 - NE);
            }
            #pragma unroll
            for (int j = 0; j < 8; j++) v[j] = (short)f2bf(s[j]);
            dst = Abf + row * KIN + c8;
        } else if (u < NA + NWU) {
            long u2 = u - NA;
            long row = u2 / 100;
            int c8 = (int)(u2 % 100) * 8;
            const float* s = Wih + row * KIN + c8;
            #pragma unroll
            for (int j = 0; j < 8; j++) v[j] = (short)f2bf(s[j]);
            dst = Wihbf + row * KIN + c8;
        } else {
            long u3 = u - NA - NWU;
            long row = u3 / 32;
            int c8 = (int)(u3 % 32) * 8;
            const float* s = Wout + row * NH + c8;
            #pragma unroll
            for (int j = 0; j < 8; j++) v[j] = (short)f2bf(s[j]);
            dst = Woutbf + row * NH + c8;
        }
        *(bf16x8*)dst = v;
    }
}

// ---------------------------------------------------------------------------
// gemm_bt128: Out[M][N] (bf16) = A[M][K](bf16) * Bw[N][K](bf16)^T + bias
// BM=BN=128, BK=32, 256 threads (4 waves, each 64x64). Reg-staged LDS tiles.
// ---------------------------------------------------------------------------
__global__ void gemm_bt128(const unsigned short* __restrict__ A,
                           const unsigned short* __restrict__ Bw,
                           const float* __restrict__ bias,
                           unsigned short* __restrict__ Out,
                           int M, int N, int K) {
    __shared__ unsigned short As[128 * 32];
    __shared__ unsigned short Bs[128 * 32];
    const int nblk = N >> 7;
    const int m0 = (blockIdx.x / nblk) << 7;
    const int n0 = (blockIdx.x % nblk) << 7;
    const int tid = threadIdx.x;
    const int lane = tid & 63;
    const int wave = tid >> 6;
    const int wm = (wave >> 1) << 6;
    const int wn = (wave & 1) << 6;
    const int nk = K >> 5;

    const int srow = tid >> 1;
    const int sbyte = (tid & 1) << 5;
    const char* ga = (const char*)(A + (long)(m0 + srow) * K) + sbyte;
    const char* gb = (const char*)(Bw + (long)(n0 + srow) * K) + sbyte;
    char* la = (char*)As + srow * 64 + sbyte;
    char* lb = (char*)Bs + srow * 64 + sbyte;

    f32x4 acc[4][4] = {};

    bf16x8 ra0 = *(const bf16x8*)(ga);
    bf16x8 ra1 = *(const bf16x8*)(ga + 16);
    bf16x8 rb0 = *(const bf16x8*)(gb);
    bf16x8 rb1 = *(const bf16x8*)(gb + 16);

    for (int kt = 0; kt < nk; kt++) {
        __syncthreads();
        *(bf16x8*)(la) = ra0;      *(bf16x8*)(la + 16) = ra1;
        *(bf16x8*)(lb) = rb0;      *(bf16x8*)(lb + 16) = rb1;
        __syncthreads();
        if (kt + 1 < nk) {  // prefetch next tile into regs; latency hides under MFMA
            const char* pa = ga + (kt + 1) * 64;
            const char* pb = gb + (kt + 1) * 64;
            ra0 = *(const bf16x8*)(pa);      ra1 = *(const bf16x8*)(pa + 16);
            rb0 = *(const bf16x8*)(pb);      rb1 = *(const bf16x8*)(pb + 16);
        }
        bf16x8 af[4], bfr[4];
        #pragma unroll
        for (int mi = 0; mi < 4; mi++)
            af[mi] = *(const bf16x8*)((const char*)As +
                        (wm + mi * 16 + (lane & 15)) * 64 + ((lane >> 4) << 4));
        #pragma unroll
        for (int ni = 0; ni < 4; ni++)
            bfr[ni] = *(const bf16x8*)((const char*)Bs +
                        (wn + ni * 16 + (lane & 15)) * 64 + ((lane >> 4) << 4));
        #pragma unroll
        for (int mi = 0; mi < 4; mi++)
            #pragma unroll
            for (int ni = 0; ni < 4; ni++)
                acc[mi][ni] = __builtin_amdgcn_mfma_f32_16x16x32_bf16(
                                  af[mi], bfr[ni], acc[mi][ni], 0, 0, 0);
    }
    // epilogue: D col = lane&15, row = (lane>>4)*4 + r  (m89-verified layout)
    #pragma unroll
    for (int ni = 0; ni < 4; ni++) {
        const int col = n0 + wn + ni * 16 + (lane & 15);
        const float bv = bias[col];
        #pragma unroll
        for (int mi = 0; mi < 4; mi++) {
            const int row = m0 + wm + mi * 16 + ((lane >> 4) << 2);
            #pragma unroll
            for (int r = 0; r < 4; r++)
                Out[(long)(row + r) * N + col] = f2bf(acc[mi][ni][r] + bv);
        }
    }
}

// ---------------------------------------------------------------------------
// gru_scan: 256 blocks (1 batch each), 512 threads (8 waves, 2/SIMD).
// Pure-VALU int8 GEMV via v_dot4_i32_i8 — no MFMA M-waste (R6: 94% of matrix
// pipe wasted on dead rows; dot4 floor 384 cyc/SIMD vs 790 MFMA).
// Thread (col = wave*32 + lane&31, kh = lane>>5): keeps its 3 W_hh rows for
// K-half kh resident as packed i8 (96 VGPR), reads its 128-B h-slice as 8
// uniform ds_read_b128 (broadcast), 3x32 sdot4 (2 partials/gate), K-halves
// combined with one shfl_xor(32)/gate. Gate tail on ALL 64 lanes (both K-half
// copies compute identical h -> no exec masking). h int8 double-buffered in
// LDS; f32 h master in regs. Quant: W scale 400 (clamp +-127), h scale 127.
// ---------------------------------------------------------------------------
__global__ __launch_bounds__(512, 2)
__attribute__((amdgpu_waves_per_eu(2, 2)))
void gru_scan(const unsigned short* __restrict__ xg,   // [51200][768] bf16 (incl biasC)
              const float* __restrict__ Whh,            // [768][256] fp32
              const float* __restrict__ bhh,            // [768]
              const int* __restrict__ lengths,          // [256]
              unsigned short* __restrict__ hout) {      // [51200][256] bf16 (masked)
    __shared__ __align__(16) unsigned char h8[2][256];  // int8 h double buffer
    const int tid = threadIdx.x;
    const int lane = tid & 63;
    const int wave = tid >> 6;               // 0..7
    const int b = blockIdx.x;
    const int col = wave * 32 + (lane & 31); // this thread's h-col
    const int kh = lane >> 5;                // K-half 0/1 (k in [kh*128, kh*128+128))

    // resident W_hh i8: W[g][d] dword d <-> k = kh*128 + d*4 + byte
    int W[3][32];
    #pragma unroll
    for (int g = 0; g < 3; g++) {
        const float* wr = Whh + (long)(g * 256 + col) * NH + kh * 128;
        #pragma unroll
        for (int d = 0; d < 32; d++) {
            const float4 f = *(const float4*)(wr + d * 4);
            unsigned pack = 0;
            #pragma unroll
            for (int j = 0; j < 4; j++) {
                const float fv = j == 0 ? f.x : j == 1 ? f.y : j == 2 ? f.z : f.w;
                int wq = (int)rintf(fv * 400.0f);
                wq = wq > 127 ? 127 : (wq < -127 ? -127 : wq);
                pack |= ((unsigned)(wq & 0xff)) << (8 * j);
            }
            W[g][d] = (int)pack;
        }
    }
    const float bhn = bhh[512 + col];        // n-gate b_hh (r,z folded into xg)
    const int len = lengths[b];
    if (tid < 128) ((unsigned*)h8)[tid] = 0u;   // zero both h buffers (512 B)

    const unsigned short* xrow = xg + (long)b * NT * G3H;
    unsigned short xv0 = xrow[col], xv1 = xrow[256 + col], xv2 = xrow[512 + col];
    float hp = 0.0f;
    const float ISC = 1.0f / (400.0f * 127.0f);
    const bool wlo = (lane < 32);

    asm volatile("s_waitcnt lgkmcnt(0)" ::: "memory");
    __builtin_amdgcn_sched_barrier(0);
    __builtin_amdgcn_s_barrier();
    __builtin_amdgcn_sched_barrier(0);

    for (int t = 0; t < NT; t++) {
        // this thread's h-slice (uniform per 32-lane half -> broadcast reads)
        const unsigned char* hb = h8[(t + 1) & 1] + kh * 128;
        int p0a = 0, p0b = 0, p1a = 0, p1b = 0, p2a = 0, p2b = 0;
        #pragma unroll
        for (int r = 0; r < 8; r++) {
            const i32x4 hv = *(const i32x4*)(hb + r * 16);
            p0a = SDOT4(hv[0], W[0][r * 4 + 0], p0a);
            p1a = SDOT4(hv[0], W[1][r * 4 + 0], p1a);
            p2a = SDOT4(hv[0], W[2][r * 4 + 0], p2a);
            p0b = SDOT4(hv[1], W[0][r * 4 + 1], p0b);
            p1b = SDOT4(hv[1], W[1][r * 4 + 1], p1b);
            p2b = SDOT4(hv[1], W[2][r * 4 + 1], p2b);
            p0a = SDOT4(hv[2], W[0][r * 4 + 2], p0a);
            p1a = SDOT4(hv[2], W[1][r * 4 + 2], p1a);
            p2a = SDOT4(hv[2], W[2][r * 4 + 2], p2a);
            p0b = SDOT4(hv[3], W[0][r * 4 + 3], p0b);
            p1b = SDOT4(hv[3], W[1][r * 4 + 3], p1b);
            p2b = SDOT4(hv[3], W[2][r * 4 + 3], p2b);
        }
        int p0 = p0a + p0b, p1 = p1a + p1b, p2 = p2a + p2b;
        p0 += __shfl_xor(p0, 32);            // combine K-halves
        p1 += __shfl_xor(p1, 32);
        p2 += __shfl_xor(p2, 32);
        // gate math on all 64 lanes (both K-half copies identical)
        const float r = sigm(bf2f(xv0) + (float)p0 * ISC);
        const float z = sigm(bf2f(xv1) + (float)p1 * ISC);
        const float n = tanh_fast(bf2f(xv2) + r * ((float)p2 * ISC + bhn));
        hp = (1.0f - z) * n + z * hp;
        if (wlo) {
            h8[t & 1][col] = (unsigned char)((int)rintf(hp * 127.0f) & 0xff);
            hout[((long)b * NT + t) * NH + col] = (t < len) ? f2bf(hp) : (unsigned short)0;
        }
        if (t + 1 < NT) {                    // prefetch next step's xg (floats past barrier)
            const unsigned short* xn = xrow + (long)(t + 1) * G3H;
            xv0 = xn[col]; xv1 = xn[256 + col]; xv2 = xn[512 + col];
        }
        // LDS-only baton: no vmcnt drain (hout stores + xg prefetch stay in flight)
        asm volatile("s_waitcnt lgkmcnt(0)" ::: "memory");
        __builtin_amdgcn_sched_barrier(0);
        __builtin_amdgcn_s_barrier();
        __builtin_amdgcn_sched_barrier(0);
    }
}

// ---------------------------------------------------------------------------
// prep2: fwe fp32 -> bf16 + word_mask (sum|row| != 0). One wave per row.
// ---------------------------------------------------------------------------
__global__ void prep2(const float* __restrict__ fwe, unsigned short* __restrict__ fwebf,
                      unsigned char* __restrict__ wmask) {
    const int row = (int)((blockIdx.x * blockDim.x + threadIdx.x) >> 6);
    const int lane = threadIdx.x & 63;
    if (row >= MROWS) return;
    const float* s = fwe + (long)row * NE;
    unsigned short* d = fwebf + (long)row * NE;
    float asum = 0.0f;
    #pragma unroll
    for (int i = 0; i < 12; i++) {
        const float v = s[lane + i * 64];
        asum += fabsf(v);
        d[lane + i * 64] = f2bf(v);
    }
    #pragma unroll
    for (int off = 32; off >= 1; off >>= 1) asum += __shfl_xor(asum, off);
    if (lane == 0) wmask[row] = (asum != 0.0f) ? 1 : 0;
}

// ---------------------------------------------------------------------------
// logits_gemm: per-batch GEMM [200 x 768] x [200 x 768]^T with mask epilogue.
// ---------------------------------------------------------------------------
__global__ void logits_gemm(const unsigned short* __restrict__ Aproj,  // [51200][768]
                            const unsigned short* __restrict__ Bfwe,   // [51200][768]
                            const int* __restrict__ fix_seq,           // [256][200]
                            const unsigned char* __restrict__ wmask,   // [51200]
                            float* __restrict__ out) {
    __shared__ unsigned short As[64 * 32];
    __shared__ unsigned short Bs[64 * 32];
    const int blk = blockIdx.x;
    const int b = blk >> 4;
    const int mt = (blk >> 2) & 3;
    const int ntile = blk & 3;
    const int t0 = mt << 6;
    const int w0 = ntile << 6;
    const int tid = threadIdx.x;
    const int lane = tid & 63;
    const int wave = tid >> 6;
    const int wm = (wave >> 1) << 5;
    const int wn = (wave & 1) << 5;

    const int srow = tid >> 2;
    const int sbyte = (tid & 3) << 4;
    const int tA = t0 + srow > 199 ? 199 : t0 + srow;   // clamp OOB rows (masked later)
    const int wB = w0 + srow > 199 ? 199 : w0 + srow;
    const char* ga = (const char*)(Aproj + ((long)b * NT + tA) * NE) + sbyte;
    const char* gb = (const char*)(Bfwe + ((long)b * NW + wB) * NE) + sbyte;
    char* la = (char*)As + srow * 64 + sbyte;
    char* lb = (char*)Bs + srow * 64 + sbyte;

    f32x4 acc[2][2] = {};
    bf16x8 ra = *(const bf16x8*)(ga);
    bf16x8 rb = *(const bf16x8*)(gb);
    for (int kt = 0; kt < 24; kt++) {
        __syncthreads();
        *(bf16x8*)(la) = ra;
        *(bf16x8*)(lb) = rb;
        __syncthreads();
        if (kt < 23) {
            ra = *(const bf16x8*)(ga + (kt + 1) * 64);
            rb = *(const bf16x8*)(gb + (kt + 1) * 64);
        }
        bf16x8 af[2], bfr[2];
        #pragma unroll
        for (int mi = 0; mi < 2; mi++)
            af[mi] = *(const bf16x8*)((const char*)As +
                        (wm + mi * 16 + (lane & 15)) * 64 + ((lane >> 4) << 4));
        #pragma unroll
        for (int ni = 0; ni < 2; ni++)
            bfr[ni] = *(const bf16x8*)((const char*)Bs +
                        (wn + ni * 16 + (lane & 15)) * 64 + ((lane >> 4) << 4));
        #pragma unroll
        for (int mi = 0; mi < 2; mi++)
            #pragma unroll
            for (int ni = 0; ni < 2; ni++)
                acc[mi][ni] = __builtin_amdgcn_mfma_f32_16x16x32_bf16(
                                  af[mi], bfr[ni], acc[mi][ni], 0, 0, 0);
    }
    // epilogue with saccade-window + valid + word masks
    #pragma unroll
    for (int mi = 0; mi < 2; mi++) {
        #pragma unroll
        for (int r = 0; r < 4; r++) {
            const int t = t0 + wm + mi * 16 + ((lane >> 4) << 2) + r;
            if (t >= NT) continue;
            const int fx = fix_seq[b * NT + t];
            #pragma unroll
            for (int ni = 0; ni < 2; ni++) {
                const int w = w0 + wn + ni * 16 + (lane & 15);
                if (w >= NW) continue;
                int d = w - fx; d = d < 0 ? -d : d;
                const bool ok = (fx != 0) && (d <= 8) && (wmask[b * NW + w] != 0);
                out[(long)b * (NT * NW) + t * NW + w] = ok ? acc[mi][ni][r] : -1e9f;
            }
        }
    }
}

// ---------------------------------------------------------------------------
// dur_kernel: dur[b,t] = dot(hout[b,t,:], W_dur) + b_dur. One wave per row.
// ---------------------------------------------------------------------------
__global__ void dur_kernel(const unsigned short* __restrict__ hout,
                           const float* __restrict__ Wdur, const float* __restrict__ bdur,
                           float* __restrict__ out) {
    const int row = (int)((blockIdx.x * blockDim.x + threadIdx.x) >> 6);
    const int lane = threadIdx.x & 63;
    if (row >= MROWS) return;
    const unsigned short* hp = hout + (long)row * NH + lane * 4;
    const uint2 hv = *(const uint2*)hp;
    const float4 wv = *(const float4*)(Wdur + lane * 4);
    float s = bf2f((unsigned short)(hv.x & 0xffff)) * wv.x
            + bf2f((unsigned short)(hv.x >> 16)) * wv.y
            + bf2f((unsigned short)(hv.y & 0xffff)) * wv.z
            + bf2f((unsigned short)(hv.y >> 16)) * wv.w;
    #pragma unroll
    for (int off = 32; off >= 1; off >>= 1) s += __shfl_down(s, off);
    if (lane == 0) out[(long)NB * NT * NW + row] = s + bdur[0];
}

// ---------------------------------------------------------------------------
extern "C" void kernel_launch(void* const* d_in, const int* in_sizes, int n_in,
                              void* d_out, int out_size, void* d_ws, size_t ws_size,
                              hipStream_t stream) {
    (void)in_sizes; (void)n_in; (void)out_size; (void)ws_size;
    const float* inputs  = (const float*)d_in[0];
    const int*   fix_seq = (const int*)d_in[1];
    const float* fwe     = (const float*)d_in[2];
    const int*   lengths = (const int*)d_in[3];
    const float* emb     = (const float*)d_in[5];
    const float* Wih     = (const float*)d_in[6];
    const float* bih     = (const float*)d_in[7];
    const float* Whh     = (const float*)d_in[8];
    const float* bhh     = (const float*)d_in[9];
    const float* Wout    = (const float*)d_in[10];
    const float* bout    = (const float*)d_in[11];
    const float* Wdur    = (const float*)d_in[12];
    const float* bdur    = (const float*)d_in[13];
    float* out = (float*)d_out;

    char* ws = (char*)d_ws;
    // region layout (bytes, all 256-aligned):
    //   [0, 81,920,000)            A_bf16 [51200][800]    -> reused as proj_bf16
    //   [81,920,000, +78,643,200)  xg_bf16 [51200][768]   -> reused as fwe_bf16
    //   [160,563,200, +26,214,400) hout_bf16 [51200][256]
    //   [186,777,600, +1,228,800)  W_ih bf16
    //   [188,006,400, +393,216)    W_out bf16
    //   [188,399,616, +51,200)     word_mask u8
    //   [188,450,816, +3,072)      biasC f32 [768]
    unsigned short* Abf    = (unsigned short*)(ws);
    unsigned short* xgbf   = (unsigned short*)(ws + 81920000);
    unsigned short* hout   = (unsigned short*)(ws + 160563200);
    unsigned short* Wihbf  = (unsigned short*)(ws + 186777600);
    unsigned short* Woutbf = (unsigned short*)(ws + 188006400);
    unsigned char*  wmask  = (unsigned char*)(ws + 188399616);
    float*          biasC  = (float*)(ws + 188450816);
    unsigned short* projbf = Abf;    // A dead after gemm1
    unsigned short* fwebf  = xgbf;   // xg dead after scan

    prep1<<<2048, 256, 0, stream>>>(inputs, fix_seq, emb, Wih, Wout, bih, bhh,
                                    Abf, Wihbf, Woutbf, biasC);
    gemm_bt128<<<400 * 6, 256, 0, stream>>>(Abf, Wihbf, biasC, xgbf, MROWS, G3H, KIN);
    gru_scan<<<256, 512, 0, stream>>>(xgbf, Whh, bhh, lengths, hout);
    gemm_bt128<<<400 * 6, 256, 0, stream>>>(hout, Woutbf, bout, projbf, MROWS, G3H, NH);
    prep2<<<12800, 256, 0, stream>>>(fwe, fwebf, wmask);
    logits_gemm<<<4096, 256, 0, stream>>>(projbf, fwebf, fix_seq, wmask, out);
    dur_kernel<<<12800, 256, 0, stream>>>(hout, Wdur, bdur, out);
}

// Round 8
// 559.411 us; speedup vs baseline: 1.0570x; 1.0570x over previous
//
#include <hip/hip_runtime.h>
#include <hip/hip_bf16.h>

typedef __attribute__((ext_vector_type(8))) short bf16x8;   // 8 bf16 in 4 VGPRs
typedef __attribute__((ext_vector_type(4))) float f32x4;    // MFMA accumulator
typedef __attribute__((ext_vector_type(4))) int   i32x4;

#define NB 256
#define NT 200
#define NW 200
#define NE 768
#define NH 256
#define NEMB 32
#define KIN 800           // E + EMB
#define G3H 768           // 3*H
#define MROWS 51200       // B*T

__device__ __forceinline__ float bf2f(unsigned short h) {
    return __uint_as_float(((unsigned)h) << 16);
}
__device__ __forceinline__ unsigned short f2bf(float f) {
    unsigned u = __float_as_uint(f);
    u += 0x7fff + ((u >> 16) & 1);   // RNE
    return (unsigned short)(u >> 16);
}
__device__ __forceinline__ float sigm(float x) { return 1.0f / (1.0f + __expf(-x)); }
__device__ __forceinline__ float tanh_fast(float x) {
    float e = __expf(2.0f * x);
    return 1.0f - 2.0f / (e + 1.0f);
}

#if __has_builtin(__builtin_amdgcn_sdot4)
__device__ __forceinline__ int SDOT4(int a, int b, int c) {
    return __builtin_amdgcn_sdot4(a, b, c, false);
}
#else
__device__ __forceinline__ int SDOT4(int a, int b, int c) {   // exact fallback
    #pragma unroll
    for (int j = 0; j < 4; j++)
        c += (int)(signed char)(a >> (8 * j)) * (int)(signed char)(b >> (8 * j));
    return c;
}
#endif

// async global->LDS, 16 B/lane. LDS dest: wave-uniform base + lane*16.
__device__ __forceinline__ void gload16(const void* g, void* l) {
    __builtin_amdgcn_global_load_lds((const __attribute__((address_space(1))) unsigned int*)g,
                                     (__attribute__((address_space(3))) unsigned int*)l,
                                     16, 0, 0);
}

// ---------------------------------------------------------------------------
// prep1: A_bf16[51200][800] = [bf16(inputs) | bf16(emb_table[fix])],
//        W_ih -> bf16 [768][800], W_out -> bf16 [768][256],
//        biasC[768] = b_ih + (row<512 ? b_hh : 0)   (b_hh r,z folded into xg)
// ---------------------------------------------------------------------------
__global__ void prep1(const float* __restrict__ inputs, const int* __restrict__ fix_seq,
                      const float* __restrict__ emb, const float* __restrict__ Wih,
                      const float* __restrict__ Wout, const float* __restrict__ bih,
                      const float* __restrict__ bhh,
                      unsigned short* __restrict__ Abf, unsigned short* __restrict__ Wihbf,
                      unsigned short* __restrict__ Woutbf, float* __restrict__ biasC) {
    const long gid0 = (long)blockIdx.x * blockDim.x + threadIdx.x;
    if (gid0 < G3H) biasC[gid0] = bih[gid0] + (gid0 < 512 ? bhh[gid0] : 0.0f);
    const long NA = (long)MROWS * 100;   // 8 cols per unit
    const long NWU = 768L * 100;
    const long NOU = 768L * 32;
    const long total = NA + NWU + NOU;
    for (long u = gid0; u < total; u += (long)gridDim.x * blockDim.x) {
        bf16x8 v;
        unsigned short* dst;
        if (u < NA) {
            long row = u / 100;
            int c8 = (int)(u % 100) * 8;
            const float* s;
            if (c8 < NE) {
                s = inputs + row * NE + c8;
            } else {
                int fx = fix_seq[row];
                s = emb + (long)fx * NEMB + (c8 - NE);
            }
            #pragma unroll
            for (int j = 0; j < 8; j++) v[j] = (short)f2bf(s[j]);
            dst = Abf + row * KIN + c8;
        } else if (u < NA + NWU) {
            long u2 = u - NA;
            long row = u2 / 100;
            int c8 = (int)(u2 % 100) * 8;
            const float* s = Wih + row * KIN + c8;
            #pragma unroll
            for (int j = 0; j < 8; j++) v[j] = (short)f2bf(s[j]);
            dst = Wihbf + row * KIN + c8;
        } else {
            long u3 = u - NA - NWU;
            long row = u3 / 32;
            int c8 = (int)(u3 % 32) * 8;
            const float* s = Wout + row * NH + c8;
            #pragma unroll
            for (int j = 0; j < 8; j++) v[j] = (short)f2bf(s[j]);
            dst = Woutbf + row * NH + c8;
        }
        *(bf16x8*)dst = v;
    }
}

// ---------------------------------------------------------------------------
// gemm_bt128: Out[M][N] (bf16) = A[M][K](bf16) * Bw[N][K](bf16)^T + bias
// BM=BN=128, BK=32, 256 threads (4 waves, each 64x64).
// m97 pattern: global_load_lds width=16 staging (thread tid covers tile byte
// tid*16: row=tid>>2, seg=tid&3; LDS dest linear = wave base + lane*16).
// XCD-bijective blockIdx swizzle (grid % 8 == 0).
// ---------------------------------------------------------------------------
__global__ __launch_bounds__(256)
void gemm_bt128(const unsigned short* __restrict__ A,
                const unsigned short* __restrict__ Bw,
                const float* __restrict__ bias,
                unsigned short* __restrict__ Out,
                int M, int N, int K) {
    __shared__ unsigned short As[128 * 32];
    __shared__ unsigned short Bs[128 * 32];
    const int bid = (int)((blockIdx.x & 7) * (gridDim.x >> 3) + (blockIdx.x >> 3));
    const int nblk = N >> 7;
    const int m0 = (bid / nblk) << 7;
    const int n0 = (bid % nblk) << 7;
    const int tid = threadIdx.x;
    const int lane = tid & 63;
    const int wave = tid >> 6;
    const int wm = (wave >> 1) << 6;
    const int wn = (wave & 1) << 6;
    const int nk = K >> 5;

    // staging: thread tid -> tile row tid>>2 (0..63), 16-B segment tid&3
    const int srow = tid >> 2;
    const int sseg = (tid & 3) << 4;
    const char* gA0 = (const char*)(A + (long)(m0 + srow) * K) + sseg;        // rows 0-63
    const char* gA1 = (const char*)(A + (long)(m0 + 64 + srow) * K) + sseg;   // rows 64-127
    const char* gB0 = (const char*)(Bw + (long)(n0 + srow) * K) + sseg;
    const char* gB1 = (const char*)(Bw + (long)(n0 + 64 + srow) * K) + sseg;
    char* lA0 = (char*)As + wave * 1024;           // bytes [0,4096) = rows 0-63
    char* lA1 = (char*)As + 4096 + wave * 1024;    // rows 64-127
    char* lB0 = (char*)Bs + wave * 1024;
    char* lB1 = (char*)Bs + 4096 + wave * 1024;

    f32x4 acc[4][4] = {};

    for (int kt = 0; kt < nk; kt++) {
        __syncthreads();                 // previous tile's reads complete
        gload16(gA0 + kt * 64, lA0);
        gload16(gA1 + kt * 64, lA1);
        gload16(gB0 + kt * 64, lB0);
        gload16(gB1 + kt * 64, lB1);
        asm volatile("s_waitcnt vmcnt(0)" ::: "memory");
        __syncthreads();                 // all waves' stages visible
        bf16x8 af[4], bfr[4];
        #pragma unroll
        for (int mi = 0; mi < 4; mi++)
            af[mi] = *(const bf16x8*)((const char*)As +
                        (wm + mi * 16 + (lane & 15)) * 64 + ((lane >> 4) << 4));
        #pragma unroll
        for (int ni = 0; ni < 4; ni++)
            bfr[ni] = *(const bf16x8*)((const char*)Bs +
                        (wn + ni * 16 + (lane & 15)) * 64 + ((lane >> 4) << 4));
        #pragma unroll
        for (int mi = 0; mi < 4; mi++)
            #pragma unroll
            for (int ni = 0; ni < 4; ni++)
                acc[mi][ni] = __builtin_amdgcn_mfma_f32_16x16x32_bf16(
                                  af[mi], bfr[ni], acc[mi][ni], 0, 0, 0);
    }
    // epilogue: D col = lane&15, row = (lane>>4)*4 + r  (m89-verified layout)
    #pragma unroll
    for (int ni = 0; ni < 4; ni++) {
        const int col = n0 + wn + ni * 16 + (lane & 15);
        const float bv = bias[col];
        #pragma unroll
        for (int mi = 0; mi < 4; mi++) {
            const int row = m0 + wm + mi * 16 + ((lane >> 4) << 2);
            #pragma unroll
            for (int r = 0; r < 4; r++)
                Out[(long)(row + r) * N + col] = f2bf(acc[mi][ni][r] + bv);
        }
    }
}

// ---------------------------------------------------------------------------
// gru_scan: 256 blocks (1 batch each), 512 threads (8 waves, 2/SIMD).
// Pure-VALU int8 GEMV via v_dot4_i32_i8 (R7; at its structural plateau).
// ---------------------------------------------------------------------------
__global__ __launch_bounds__(512, 2)
__attribute__((amdgpu_waves_per_eu(2, 2)))
void gru_scan(const unsigned short* __restrict__ xg,   // [51200][768] bf16 (incl biasC)
              const float* __restrict__ Whh,            // [768][256] fp32
              const float* __restrict__ bhh,            // [768]
              const int* __restrict__ lengths,          // [256]
              unsigned short* __restrict__ hout) {      // [51200][256] bf16 (masked)
    __shared__ __align__(16) unsigned char h8[2][256];  // int8 h double buffer
    const int tid = threadIdx.x;
    const int lane = tid & 63;
    const int wave = tid >> 6;               // 0..7
    const int b = blockIdx.x;
    const int col = wave * 32 + (lane & 31); // this thread's h-col
    const int kh = lane >> 5;                // K-half 0/1

    int W[3][32];
    #pragma unroll
    for (int g = 0; g < 3; g++) {
        const float* wr = Whh + (long)(g * 256 + col) * NH + kh * 128;
        #pragma unroll
        for (int d = 0; d < 32; d++) {
            const float4 f = *(const float4*)(wr + d * 4);
            unsigned pack = 0;
            #pragma unroll
            for (int j = 0; j < 4; j++) {
                const float fv = j == 0 ? f.x : j == 1 ? f.y : j == 2 ? f.z : f.w;
                int wq = (int)rintf(fv * 400.0f);
                wq = wq > 127 ? 127 : (wq < -127 ? -127 : wq);
                pack |= ((unsigned)(wq & 0xff)) << (8 * j);
            }
            W[g][d] = (int)pack;
        }
    }
    const float bhn = bhh[512 + col];        // n-gate b_hh (r,z folded into xg)
    const int len = lengths[b];
    if (tid < 128) ((unsigned*)h8)[tid] = 0u;   // zero both h buffers (512 B)

    const unsigned short* xrow = xg + (long)b * NT * G3H;
    unsigned short xv0 = xrow[col], xv1 = xrow[256 + col], xv2 = xrow[512 + col];
    float hp = 0.0f;
    const float ISC = 1.0f / (400.0f * 127.0f);
    const bool wlo = (lane < 32);

    asm volatile("s_waitcnt lgkmcnt(0)" ::: "memory");
    __builtin_amdgcn_sched_barrier(0);
    __builtin_amdgcn_s_barrier();
    __builtin_amdgcn_sched_barrier(0);

    for (int t = 0; t < NT; t++) {
        const unsigned char* hb = h8[(t + 1) & 1] + kh * 128;
        int p0a = 0, p0b = 0, p1a = 0, p1b = 0, p2a = 0, p2b = 0;
        #pragma unroll
        for (int r = 0; r < 8; r++) {
            const i32x4 hv = *(const i32x4*)(hb + r * 16);
            p0a = SDOT4(hv[0], W[0][r * 4 + 0], p0a);
            p1a = SDOT4(hv[0], W[1][r * 4 + 0], p1a);
            p2a = SDOT4(hv[0], W[2][r * 4 + 0], p2a);
            p0b = SDOT4(hv[1], W[0][r * 4 + 1], p0b);
            p1b = SDOT4(hv[1], W[1][r * 4 + 1], p1b);
            p2b = SDOT4(hv[1], W[2][r * 4 + 1], p2b);
            p0a = SDOT4(hv[2], W[0][r * 4 + 2], p0a);
            p1a = SDOT4(hv[2], W[1][r * 4 + 2], p1a);
            p2a = SDOT4(hv[2], W[2][r * 4 + 2], p2a);
            p0b = SDOT4(hv[3], W[0][r * 4 + 3], p0b);
            p1b = SDOT4(hv[3], W[1][r * 4 + 3], p1b);
            p2b = SDOT4(hv[3], W[2][r * 4 + 3], p2b);
        }
        int p0 = p0a + p0b, p1 = p1a + p1b, p2 = p2a + p2b;
        p0 += __shfl_xor(p0, 32);            // combine K-halves
        p1 += __shfl_xor(p1, 32);
        p2 += __shfl_xor(p2, 32);
        const float r = sigm(bf2f(xv0) + (float)p0 * ISC);
        const float z = sigm(bf2f(xv1) + (float)p1 * ISC);
        const float n = tanh_fast(bf2f(xv2) + r * ((float)p2 * ISC + bhn));
        hp = (1.0f - z) * n + z * hp;
        if (wlo) {
            h8[t & 1][col] = (unsigned char)((int)rintf(hp * 127.0f) & 0xff);
            hout[((long)b * NT + t) * NH + col] = (t < len) ? f2bf(hp) : (unsigned short)0;
        }
        if (t + 1 < NT) {
            const unsigned short* xn = xrow + (long)(t + 1) * G3H;
            xv0 = xn[col]; xv1 = xn[256 + col]; xv2 = xn[512 + col];
        }
        asm volatile("s_waitcnt lgkmcnt(0)" ::: "memory");
        __builtin_amdgcn_sched_barrier(0);
        __builtin_amdgcn_s_barrier();
        __builtin_amdgcn_sched_barrier(0);
    }
}

// ---------------------------------------------------------------------------
// prep2: fwe fp32 -> bf16 + word_mask (sum|row| != 0). One wave per row.
// ---------------------------------------------------------------------------
__global__ void prep2(const float* __restrict__ fwe, unsigned short* __restrict__ fwebf,
                      unsigned char* __restrict__ wmask) {
    const int row = (int)((blockIdx.x * blockDim.x + threadIdx.x) >> 6);
    const int lane = threadIdx.x & 63;
    if (row >= MROWS) return;
    const float* s = fwe + (long)row * NE;
    unsigned short* d = fwebf + (long)row * NE;
    float asum = 0.0f;
    #pragma unroll
    for (int i = 0; i < 12; i++) {
        const float v = s[lane + i * 64];
        asum += fabsf(v);
        d[lane + i * 64] = f2bf(v);
    }
    #pragma unroll
    for (int off = 32; off >= 1; off >>= 1) asum += __shfl_xor(asum, off);
    if (lane == 0) wmask[row] = (asum != 0.0f) ? 1 : 0;
}

// ---------------------------------------------------------------------------
// logits_gemm: per-batch GEMM [200 x 768] x [200 x 768]^T with mask epilogue.
// ---------------------------------------------------------------------------
__global__ void logits_gemm(const unsigned short* __restrict__ Aproj,  // [51200][768]
                            const unsigned short* __restrict__ Bfwe,   // [51200][768]
                            const int* __restrict__ fix_seq,           // [256][200]
                            const unsigned char* __restrict__ wmask,   // [51200]
                            float* __restrict__ out) {
    __shared__ unsigned short As[64 * 32];
    __shared__ unsigned short Bs[64 * 32];
    const int blk = blockIdx.x;
    const int b = blk >> 4;
    const int mt = (blk >> 2) & 3;
    const int ntile = blk & 3;
    const int t0 = mt << 6;
    const int w0 = ntile << 6;
    const int tid = threadIdx.x;
    const int lane = tid & 63;
    const int wave = tid >> 6;
    const int wm = (wave >> 1) << 5;
    const int wn = (wave & 1) << 5;

    const int srow = tid >> 2;
    const int sbyte = (tid & 3) << 4;
    const int tA = t0 + srow > 199 ? 199 : t0 + srow;   // clamp OOB rows (masked later)
    const int wB = w0 + srow > 199 ? 199 : w0 + srow;
    const char* ga = (const char*)(Aproj + ((long)b * NT + tA) * NE) + sbyte;
    const char* gb = (const char*)(Bfwe + ((long)b * NW + wB) * NE) + sbyte;
    char* la = (char*)As + srow * 64 + sbyte;
    char* lb = (char*)Bs + srow * 64 + sbyte;

    f32x4 acc[2][2] = {};
    bf16x8 ra = *(const bf16x8*)(ga);
    bf16x8 rb = *(const bf16x8*)(gb);
    for (int kt = 0; kt < 24; kt++) {
        __syncthreads();
        *(bf16x8*)(la) = ra;
        *(bf16x8*)(lb) = rb;
        __syncthreads();
        if (kt < 23) {
            ra = *(const bf16x8*)(ga + (kt + 1) * 64);
            rb = *(const bf16x8*)(gb + (kt + 1) * 64);
        }
        bf16x8 af[2], bfr[2];
        #pragma unroll
        for (int mi = 0; mi < 2; mi++)
            af[mi] = *(const bf16x8*)((const char*)As +
                        (wm + mi * 16 + (lane & 15)) * 64 + ((lane >> 4) << 4));
        #pragma unroll
        for (int ni = 0; ni < 2; ni++)
            bfr[ni] = *(const bf16x8*)((const char*)Bs +
                        (wn + ni * 16 + (lane & 15)) * 64 + ((lane >> 4) << 4));
        #pragma unroll
        for (int mi = 0; mi < 2; mi++)
            #pragma unroll
            for (int ni = 0; ni < 2; ni++)
                acc[mi][ni] = __builtin_amdgcn_mfma_f32_16x16x32_bf16(
                                  af[mi], bfr[ni], acc[mi][ni], 0, 0, 0);
    }
    // epilogue with saccade-window + valid + word masks
    #pragma unroll
    for (int mi = 0; mi < 2; mi++) {
        #pragma unroll
        for (int r = 0; r < 4; r++) {
            const int t = t0 + wm + mi * 16 + ((lane >> 4) << 2) + r;
            if (t >= NT) continue;
            const int fx = fix_seq[b * NT + t];
            #pragma unroll
            for (int ni = 0; ni < 2; ni++) {
                const int w = w0 + wn + ni * 16 + (lane & 15);
                if (w >= NW) continue;
                int d = w - fx; d = d < 0 ? -d : d;
                const bool ok = (fx != 0) && (d <= 8) && (wmask[b * NW + w] != 0);
                out[(long)b * (NT * NW) + t * NW + w] = ok ? acc[mi][ni][r] : -1e9f;
            }
        }
    }
}

// ---------------------------------------------------------------------------
// dur_kernel: dur[b,t] = dot(hout[b,t,:], W_dur) + b_dur. One wave per row.
// ---------------------------------------------------------------------------
__global__ void dur_kernel(const unsigned short* __restrict__ hout,
                           const float* __restrict__ Wdur, const float* __restrict__ bdur,
                           float* __restrict__ out) {
    const int row = (int)((blockIdx.x * blockDim.x + threadIdx.x) >> 6);
    const int lane = threadIdx.x & 63;
    if (row >= MROWS) return;
    const unsigned short* hp = hout + (long)row * NH + lane * 4;
    const uint2 hv = *(const uint2*)hp;
    const float4 wv = *(const float4*)(Wdur + lane * 4);
    float s = bf2f((unsigned short)(hv.x & 0xffff)) * wv.x
            + bf2f((unsigned short)(hv.x >> 16)) * wv.y
            + bf2f((unsigned short)(hv.y & 0xffff)) * wv.z
            + bf2f((unsigned short)(hv.y >> 16)) * wv.w;
    #pragma unroll
    for (int off = 32; off >= 1; off >>= 1) s += __shfl_down(s, off);
    if (lane == 0) out[(long)NB * NT * NW + row] = s + bdur[0];
}

// ---------------------------------------------------------------------------
extern "C" void kernel_launch(void* const* d_in, const int* in_sizes, int n_in,
                              void* d_out, int out_size, void* d_ws, size_t ws_size,
                              hipStream_t stream) {
    (void)in_sizes; (void)n_in; (void)out_size; (void)ws_size;
    const float* inputs  = (const float*)d_in[0];
    const int*   fix_seq = (const int*)d_in[1];
    const float* fwe     = (const float*)d_in[2];
    const int*   lengths = (const int*)d_in[3];
    const float* emb     = (const float*)d_in[5];
    const float* Wih     = (const float*)d_in[6];
    const float* bih     = (const float*)d_in[7];
    const float* Whh     = (const float*)d_in[8];
    const float* bhh     = (const float*)d_in[9];
    const float* Wout    = (const float*)d_in[10];
    const float* bout    = (const float*)d_in[11];
    const float* Wdur    = (const float*)d_in[12];
    const float* bdur    = (const float*)d_in[13];
    float* out = (float*)d_out;

    char* ws = (char*)d_ws;
    // region layout (bytes, all 256-aligned):
    //   [0, 81,920,000)            A_bf16 [51200][800]    -> reused as proj_bf16
    //   [81,920,000, +78,643,200)  xg_bf16 [51200][768]   -> reused as fwe_bf16
    //   [160,563,200, +26,214,400) hout_bf16 [51200][256]
    //   [186,777,600, +1,228,800)  W_ih bf16
    //   [188,006,400, +393,216)    W_out bf16
    //   [188,399,616, +51,200)     word_mask u8
    //   [188,450,816, +3,072)      biasC f32 [768]
    unsigned short* Abf    = (unsigned short*)(ws);
    unsigned short* xgbf   = (unsigned short*)(ws + 81920000);
    unsigned short* hout   = (unsigned short*)(ws + 160563200);
    unsigned short* Wihbf  = (unsigned short*)(ws + 186777600);
    unsigned short* Woutbf = (unsigned short*)(ws + 188006400);
    unsigned char*  wmask  = (unsigned char*)(ws + 188399616);
    float*          biasC  = (float*)(ws + 188450816);
    unsigned short* projbf = Abf;    // A dead after gemm1
    unsigned short* fwebf  = xgbf;   // xg dead after scan

    prep1<<<2048, 256, 0, stream>>>(inputs, fix_seq, emb, Wih, Wout, bih, bhh,
                                    Abf, Wihbf, Woutbf, biasC);
    gemm_bt128<<<400 * 6, 256, 0, stream>>>(Abf, Wihbf, biasC, xgbf, MROWS, G3H, KIN);
    gru_scan<<<256, 512, 0, stream>>>(xgbf, Whh, bhh, lengths, hout);
    gemm_bt128<<<400 * 6, 256, 0, stream>>>(hout, Woutbf, bout, projbf, MROWS, G3H, NH);
    prep2<<<12800, 256, 0, stream>>>(fwe, fwebf, wmask);
    logits_gemm<<<4096, 256, 0, stream>>>(projbf, fwebf, fix_seq, wmask, out);
    dur_kernel<<<12800, 256, 0, stream>>>(hout, Wdur, bdur, out);
}